// Round 2
// baseline (80.135 us; speedup 1.0000x reference)
//
#include <hip/hip_runtime.h>
#include <math.h>

#define BLOCK 256      // 2 mode-groups x 128 l-lanes
#define LANES 128      // l-lanes per group; recurrence stride is LANES
#define CHUNK 32       // l-values per thread; LANES*CHUNK = 4096 = L
#define NGROUP 2

typedef float f32x2 __attribute__((ext_vector_type(2)));

// out[h,l] = 2 * Re( sum_n C'_{hn} * exp(dtA_{hn})^l )
//
// Thread (grp, lane) of block h handles l = base + lane + LANES*j and the
// mode-pair range [grp*npair/2, (grp+1)*npair/2). Real 2nd-order recurrence:
//     r_{j+1} = 2Re(W) r_j - |W|^2 r_{j-1},   W = w^LANES, |W| < 1 (stable).
// Two independent packed chains run per thread (4 modes) so dependent-FMA
// latency is overlapped; group 1's partial sums are reduced via LDS.
// Occupancy: 1024 blocks x 4 waves -> 4 waves/SIMD (vs 2 before).
__global__ __launch_bounds__(BLOCK, 4) void s4_vandermonde(
    const float* __restrict__ log_dt,
    const float* __restrict__ C_re,
    const float* __restrict__ C_im,
    const float* __restrict__ log_A_re,
    const float* __restrict__ A_im,
    float* __restrict__ out,
    int n, int L)
{
    const int h    = blockIdx.x;
    const int base = blockIdx.y * (LANES * CHUNK);
    const int tid  = threadIdx.x;
    const int grp  = tid >> 7;            // 0 or 1
    const int lane = tid & (LANES - 1);

    extern __shared__ float smem[];
    const int ns = (n + 1) & ~1;          // even stride so f32x2 loads stay 8B-aligned
    float* s_x  = smem;                   // Re(dtA)
    float* s_y  = s_x  + ns;              // Im(dtA)
    float* s_cr = s_y  + ns;              // Re(C')
    float* s_ci = s_cr + ns;              // Im(C')
    float* s_wr = s_ci + ns;              // Re(W)   (W = w^LANES)
    float* s_wi = s_wr + ns;              // Im(W)
    float* s_a  = s_wi + ns;              // 2*Re(W)
    float* s_nb = s_a  + ns;              // -|W|^2
    float* s_part = s_nb + ns;            // [CHUNK][LANES] group-1 partials (16 KB)

    // Per-(h,n) precompute by first n threads.
    for (int i = tid; i < n; i += BLOCK) {
        const float dt  = __expf(log_dt[h]);
        const float Are = -__expf(log_A_re[(size_t)h * n + i]);
        const float Aim = A_im[(size_t)h * n + i];
        const float x = Are * dt;           // always < 0 (decay)
        const float y = Aim * dt;

        // w = exp(dtA)
        float ex = __expf(x), sy, cy;
        __sincosf(y, &sy, &cy);
        const float er = ex * cy, ei = ex * sy;

        // C' = C * (w - 1) / A   (|A|^2 >= Aim^2 = 1, no div hazard)
        const float numr = er - 1.0f, numi = ei;
        const float inv  = 1.0f / (Are * Are + Aim * Aim);
        const float dr = (numr * Are + numi * Aim) * inv;
        const float di = (numi * Are - numr * Aim) * inv;
        const float Cr = C_re[(size_t)h * n + i];
        const float Ci = C_im[(size_t)h * n + i];
        s_cr[i] = Cr * dr - Ci * di;
        s_ci[i] = Cr * di + Ci * dr;
        s_x[i] = x;
        s_y[i] = y;

        // W = w^LANES = exp(dtA * LANES)
        float exs = __expf(x * (float)LANES), ss, cs;
        __sincosf(y * (float)LANES, &ss, &cs);
        s_wr[i] = exs * cs;
        s_wi[i] = exs * ss;
        s_a[i]  = 2.0f * exs * cs;          // 2 Re(W)
        s_nb[i] = -(exs * exs);             // -|W|^2 = -exp(2*LANES*x)
    }
    __syncthreads();

    // Packed per-pair constant views (pair p = modes 2p, 2p+1).
    const f32x2* x2  = (const f32x2*)s_x;
    const f32x2* y2  = (const f32x2*)s_y;
    const f32x2* cr2 = (const f32x2*)s_cr;
    const f32x2* ci2 = (const f32x2*)s_ci;
    const f32x2* wr2 = (const f32x2*)s_wr;
    const f32x2* wi2 = (const f32x2*)s_wi;
    const f32x2* a2  = (const f32x2*)s_a;
    const f32x2* nb2 = (const f32x2*)s_nb;

    float acc[CHUNK];
#pragma unroll
    for (int j = 0; j < CHUNK; ++j) acc[j] = 0.0f;

    const float fl = (float)(base + lane);  // starting l for this thread
    const int npair = n >> 1;
    const int p0 = (npair * grp) / NGROUP;
    const int p1 = (npair * (grp + 1)) / NGROUP;

    // scalar sincos outputs (can't take address of vector elements)
#define INIT_PAIR(p, rp, rc, a, nb)                                    \
    {                                                                  \
        const f32x2 xf = x2[p] * fl;                                   \
        const f32x2 yf = y2[p] * fl;                                   \
        float e0 = __expf(xf.x), e1 = __expf(xf.y);                    \
        float sn0, cs0, sn1, cs1;                                      \
        __sincosf(yf.x, &sn0, &cs0);                                   \
        __sincosf(yf.y, &sn1, &cs1);                                   \
        const f32x2 e  = { e0, e1 };                                   \
        const f32x2 sn = { sn0, sn1 };                                 \
        const f32x2 cs = { cs0, cs1 };                                 \
        const f32x2 cr = cr2[p], ci = ci2[p];                          \
        const f32x2 sr = e * (cr * cs - ci * sn);                      \
        const f32x2 si = e * (cr * sn + ci * cs);                      \
        rp = sr;                                                       \
        rc = sr * wr2[p] - si * wi2[p];                                \
        a  = a2[p];                                                    \
        nb = nb2[p];                                                   \
    }

    int p = p0;
    // two independent packed chains (4 modes) per iteration
    for (; p + 1 < p1; p += 2) {
        f32x2 rpA, rcA, aA, nbA, rpB, rcB, aB, nbB;
        INIT_PAIR(p,     rpA, rcA, aA, nbA);
        INIT_PAIR(p + 1, rpB, rcB, aB, nbB);
        acc[0] += (rpA.x + rpA.y) + (rpB.x + rpB.y);
        acc[1] += (rcA.x + rcA.y) + (rcB.x + rcB.y);
#pragma unroll
        for (int j = 2; j < CHUNK; ++j) {
            const f32x2 rnA = __builtin_elementwise_fma(aA, rcA, nbA * rpA);
            const f32x2 rnB = __builtin_elementwise_fma(aB, rcB, nbB * rpB);
            const f32x2 t = rnA + rnB;
            acc[j] += t.x + t.y;
            rpA = rcA; rcA = rnA;
            rpB = rcB; rcB = rnB;
        }
    }
    if (p < p1) {   // leftover single pair
        f32x2 rp_, rc_, a_, nb_;
        INIT_PAIR(p, rp_, rc_, a_, nb_);
        acc[0] += rp_.x + rp_.y;
        acc[1] += rc_.x + rc_.y;
#pragma unroll
        for (int j = 2; j < CHUNK; ++j) {
            const f32x2 rn = __builtin_elementwise_fma(a_, rc_, nb_ * rp_);
            acc[j] += rn.x + rn.y;
            rp_ = rc_; rc_ = rn;
        }
    }
    // odd-n tail mode -> last group, scalar chain (n=32 in practice)
    if ((n & 1) && grp == NGROUP - 1) {
        const int i = n - 1;
        const float x = s_x[i], y = s_y[i];
        float e0 = __expf(x * fl), s0, c0;
        __sincosf(y * fl, &s0, &c0);
        const float cr = s_cr[i], ci = s_ci[i];
        const float sr = e0 * (cr * c0 - ci * s0);
        const float si = e0 * (cr * s0 + ci * c0);
        float rp_ = sr;
        float rc_ = sr * s_wr[i] - si * s_wi[i];
        const float a_ = s_a[i], nb_ = s_nb[i];
        acc[0] += rp_;
        acc[1] += rc_;
#pragma unroll
        for (int j = 2; j < CHUNK; ++j) {
            const float rn = fmaf(a_, rc_, nb_ * rp_);
            acc[j] += rn;
            rp_ = rc_;
            rc_ = rn;
        }
    }
#undef INIT_PAIR

    // cross-group reduction: group 1 -> LDS, group 0 adds and stores.
    if (grp == 1) {
#pragma unroll
        for (int j = 0; j < CHUNK; ++j)
            s_part[j * LANES + lane] = acc[j];   // [j][lane]: conflict-free
    }
    __syncthreads();
    if (grp == 0) {
        float* o = out + (size_t)h * L + base + lane;
#pragma unroll
        for (int j = 0; j < CHUNK; ++j) {
            const int l = base + lane + j * LANES;
            if (l < L) o[(size_t)j * LANES] = 2.0f * (acc[j] + s_part[j * LANES + lane]);
        }
    }
}

extern "C" void kernel_launch(void* const* d_in, const int* in_sizes, int n_in,
                              void* d_out, int out_size, void* d_ws, size_t ws_size,
                              hipStream_t stream) {
    const float* log_dt   = (const float*)d_in[0];
    const float* C_re     = (const float*)d_in[1];
    const float* C_im     = (const float*)d_in[2];
    const float* log_A_re = (const float*)d_in[3];
    const float* A_im     = (const float*)d_in[4];
    float* out = (float*)d_out;

    const int H = in_sizes[0];          // 1024
    const int n = in_sizes[1] / H;      // 32
    const int L = out_size / H;         // 4096 (avoid device read of d_in[5])

    const int lchunks = (L + LANES * CHUNK - 1) / (LANES * CHUNK);
    dim3 grid(H, lchunks);
    const int ns = (n + 1) & ~1;
    const size_t lds = ((size_t)8 * ns + (size_t)CHUNK * LANES) * sizeof(float);
    s4_vandermonde<<<grid, BLOCK, lds, stream>>>(
        log_dt, C_re, C_im, log_A_re, A_im, out, n, L);
}